// Round 3
// baseline (2184.012 us; speedup 1.0000x reference)
//
#include <hip/hip_runtime.h>
#include <float.h>
#include <math.h>

#define NQ 2048
#define NT 100000
#define DIM 512
#define KTOP 5
#define QTILE 128
#define TTILE 128
#define NTPC 13             // t-tiles per chunk
#define CHUNK (NTPC*TTILE)  // 1664
#define NCH 62              // 62*1664 = 103168 >= 100000
#define TPAD 103168
#define QBLKS 16            // NQ/128

typedef float f32x4 __attribute__((ext_vector_type(4)));
typedef short s16x8 __attribute__((ext_vector_type(8)));
typedef unsigned int u32;

__device__ __forceinline__ bool lt_pair(float v1, int i1, float v2, int i2) {
  return v1 < v2 || (v1 == v2 && i1 < i2);
}

__device__ __forceinline__ void ins5(float* tv, int* tix, float sc, int idx) {
  if (lt_pair(sc, idx, tv[4], tix[4])) {
    tv[4] = sc; tix[4] = idx;
#pragma unroll
    for (int p = 4; p > 0; --p)
      if (lt_pair(tv[p], tix[p], tv[p - 1], tix[p - 1])) {
        float tf = tv[p]; tv[p] = tv[p - 1]; tv[p - 1] = tf;
        int tn = tix[p]; tix[p] = tix[p - 1]; tix[p - 1] = tn;
      }
  }
}

__device__ __forceinline__ void merge5(float* av, int* ai, const float* bv, const int* bi) {
  float nv[5]; int ni[5];
#pragma unroll
  for (int s = 0; s < 5; ++s) {
    if (lt_pair(av[s], ai[s], bv[4 - s], bi[4 - s])) { nv[s] = av[s]; ni[s] = ai[s]; }
    else { nv[s] = bv[4 - s]; ni[s] = bi[4 - s]; }
  }
#pragma unroll
  for (int a = 0; a < 5; ++a)
#pragma unroll
    for (int b = 0; b < 4 - a; ++b)
      if (lt_pair(nv[b + 1], ni[b + 1], nv[b], ni[b])) {
        float tf = nv[b]; nv[b] = nv[b + 1]; nv[b + 1] = tf;
        int tn = ni[b]; ni[b] = ni[b + 1]; ni[b + 1] = tn;
      }
#pragma unroll
  for (int s = 0; s < 5; ++s) { av[s] = nv[s]; ai[s] = ni[s]; }
}

__device__ __forceinline__ void gload16(const void* g, void* l) {
  __builtin_amdgcn_global_load_lds(
      (const __attribute__((address_space(1))) unsigned int*)g,
      (__attribute__((address_space(3))) unsigned int*)l, 16, 0, 0);
}

// ---------------- convert: fp32 -> frag-major (hi, mid) bf16 + fused norms ----
// One row per wave (512 floats = 64 lanes x 8). Frag-major layout:
//   dst short-offset = ((blk128*16 + kbi)*512 + tile*64 + quad*16 + m) * 8
// which equals the LDS order knn_mfma's MFMA fragment reads expect, so the
// main kernel can stage with pure global_load_lds (global order == LDS order).
__global__ __launch_bounds__(256) void convert_kernel(
    const float* __restrict__ x, const float* __restrict__ T,
    short* __restrict__ xhi, short* __restrict__ xmid,
    short* __restrict__ thi, short* __restrict__ tmid,
    float* __restrict__ t2, float* __restrict__ x2) {
  int gwave = (blockIdx.x * 256 + threadIdx.x) >> 6;
  int l = threadIdx.x & 63;
  if (gwave >= TPAD + NQ) return;
  bool isT = gwave < TPAD;
  int r = isT ? gwave : gwave - TPAD;
  int nsrc = isT ? NT : NQ;
  int rs = r < nsrc ? r : nsrc - 1;   // clamp padded rows
  const float* src = (isT ? T : x) + (size_t)rs * DIM + l * 8;

  f32x4 a = *(const f32x4*)src;
  f32x4 b = *(const f32x4*)(src + 4);
  float e[8] = {a[0], a[1], a[2], a[3], b[0], b[1], b[2], b[3]};
  s16x8 hv, mv;
  float ss = 0.f;
#pragma unroll
  for (int i = 0; i < 8; ++i) {
    ss = fmaf(e[i], e[i], ss);
    u32 u = __builtin_bit_cast(u32, e[i]);
    u32 rr = u + 0x7FFFu + ((u >> 16) & 1u);       // RNE to bf16
    float resid = e[i] - __builtin_bit_cast(float, rr & 0xFFFF0000u);
    u32 u2 = __builtin_bit_cast(u32, resid);
    u32 r2 = u2 + 0x7FFFu + ((u2 >> 16) & 1u);
    hv[i] = (short)(rr >> 16);
    mv[i] = (short)(r2 >> 16);
  }
  // norm reduce across wave
#pragma unroll
  for (int off = 32; off > 0; off >>= 1) ss += __shfl_down(ss, off, 64);
  if (l == 0 && r < nsrc) (isT ? t2 : x2)[r] = ss;

  int blk = r >> 7, rt = r & 127, tile = rt >> 4, m = rt & 15;
  int kbi = l >> 2, quad = l & 3;
  size_t off = (((size_t)(blk * 16 + kbi)) * 512 + tile * 64 + quad * 16 + m) * 8;
  *(s16x8*)((isT ? thi : xhi) + off) = hv;
  *(s16x8*)((isT ? tmid : xmid) + off) = mv;
}

// ---------------- main: bf16x3 MFMA GEMM (pre-split inputs) + fused top-5 ----
// LDS (shorts): A_hi [0,4096) A_mid [4096,8192) B_hi [8192,12288) B_mid [12288,16384)
__global__ __launch_bounds__(256) void knn_mfma(
    const short* __restrict__ xhi, const short* __restrict__ xmid,
    const short* __restrict__ thi, const short* __restrict__ tmid,
    const float* __restrict__ t2g,
    float* __restrict__ pvals, int* __restrict__ pidx) {
  __shared__ short lds_s[16384];   // 32 KB

  const int tid = threadIdx.x;
  const int w = tid >> 6;
  const int l = tid & 63;
  const int q0 = blockIdx.x * QTILE;
  const int wr = (w >> 1) * 64;    // wave row base within block
  const int wc = (w & 1) * 64;     // wave col base within t-tile

  float tv[KTOP]; int tix[KTOP];
#pragma unroll
  for (int s = 0; s < KTOP; ++s) { tv[s] = FLT_MAX; tix[s] = 0x7FFFFFFF; }

  for (int tt = 0; tt < NTPC; ++tt) {
    const int bblk = blockIdx.y * NTPC + tt;      // global 128-row t-tile index
    const int jbase = bblk * TTILE;
    f32x4 acc[4][4];
#pragma unroll
    for (int i = 0; i < 4; ++i)
#pragma unroll
      for (int j = 0; j < 4; ++j) acc[i][j] = (f32x4){0.f, 0.f, 0.f, 0.f};

#pragma unroll 1
    for (int kbi = 0; kbi < 16; ++kbi) {
      __syncthreads();  // prior frag/epilogue reads done before overwrite
      size_t abase = ((size_t)(blockIdx.x * 16 + kbi) * 512) * 8;
      size_t bbase = ((size_t)(bblk * 16 + kbi) * 512) * 8;
#pragma unroll
      for (int g = 0; g < 2; ++g) {
        int fo = (g * 256 + w * 64) * 8;  // wave-uniform LDS/frag offset (shorts)
        int po = fo + l * 8;              // per-lane global offset
        gload16(xhi + abase + po, lds_s + fo);
        gload16(xmid + abase + po, lds_s + 4096 + fo);
        gload16(thi + bbase + po, lds_s + 8192 + fo);
        gload16(tmid + bbase + po, lds_s + 12288 + fo);
      }
      __syncthreads();  // drains vmcnt: staged data visible

      s16x8 ah[4], am[4];
      const int arow = wr >> 4;
#pragma unroll
      for (int i = 0; i < 4; ++i) {
        ah[i] = *(const s16x8*)(lds_s + ((arow + i) * 64 + l) * 8);
        am[i] = *(const s16x8*)(lds_s + 4096 + ((arow + i) * 64 + l) * 8);
      }
#pragma unroll
      for (int j = 0; j < 4; ++j) {
        int btile = (wc >> 4) + j;
        s16x8 bh = *(const s16x8*)(lds_s + 8192 + (btile * 64 + l) * 8);
        s16x8 bm = *(const s16x8*)(lds_s + 12288 + (btile * 64 + l) * 8);
#pragma unroll
        for (int i = 0; i < 4; ++i) {
          acc[i][j] = __builtin_amdgcn_mfma_f32_16x16x32_bf16(ah[i], bh, acc[i][j], 0, 0, 0);
          acc[i][j] = __builtin_amdgcn_mfma_f32_16x16x32_bf16(ah[i], bm, acc[i][j], 0, 0, 0);
          acc[i][j] = __builtin_amdgcn_mfma_f32_16x16x32_bf16(am[i], bh, acc[i][j], 0, 0, 0);
        }
      }
    }

    // epilogue: transpose C through wave-private LDS scratch; per-lane top-5
    __syncthreads();
    float* scr = ((float*)lds_s) + w * 1280;  // 64 rows x 20 (pad)
#pragma unroll
    for (int jj = 0; jj < 4; ++jj) {
      int colg = jbase + wc + jj * 16 + (l & 15);
      int cc = colg < NT ? colg : NT - 1;
      float t2v = t2g[cc];
      bool valid = colg < NT;
#pragma unroll
      for (int i = 0; i < 4; ++i)
#pragma unroll
        for (int r = 0; r < 4; ++r) {
          float sc = valid ? fmaf(-2.f, acc[i][jj][r], t2v) : FLT_MAX;
          int rowl = i * 16 + ((l >> 4) << 2) + r;
          scr[rowl * 20 + (l & 15)] = sc;
        }
      int cbg = jbase + wc + jj * 16;
#pragma unroll
      for (int c4 = 0; c4 < 4; ++c4) {
        f32x4 rv = *(const f32x4*)(scr + l * 20 + c4 * 4);
#pragma unroll
        for (int c = 0; c < 4; ++c) ins5(tv, tix, rv[c], cbg + c4 * 4 + c);
      }
    }
  }

  // cross-wave merge: waves (0,1) share rows 0-63, (2,3) rows 64-127
  __syncthreads();
  float* ms = (float*)lds_s;
  int* msi = (int*)lds_s + 640;
  if (w & 1) {
    int rid = wr + l;
#pragma unroll
    for (int s = 0; s < KTOP; ++s) { ms[rid * 5 + s] = tv[s]; msi[rid * 5 + s] = tix[s]; }
  }
  __syncthreads();
  if (!(w & 1)) {
    int rid = wr + l;
    float ov[KTOP]; int oi[KTOP];
#pragma unroll
    for (int s = 0; s < KTOP; ++s) { ov[s] = ms[rid * 5 + s]; oi[s] = msi[rid * 5 + s]; }
    merge5(tv, tix, ov, oi);
    int q = q0 + rid;
    size_t base = ((size_t)q * NCH + blockIdx.y) * KTOP;
#pragma unroll
    for (int s = 0; s < KTOP; ++s) { pvals[base + s] = tv[s]; pidx[base + s] = tix[s]; }
  }
}

// ---------------- final merge: 310 candidates -> 5, write outputs ----------------
__global__ __launch_bounds__(256) void knn_merge(
    const float* __restrict__ pvals, const int* __restrict__ pidx,
    const float* __restrict__ x2, const int* __restrict__ labels,
    float* __restrict__ out) {
  int q = blockIdx.x * 256 + threadIdx.x;
  if (q >= NQ) return;
  float tv[KTOP]; int tix[KTOP];
#pragma unroll
  for (int s = 0; s < KTOP; ++s) { tv[s] = FLT_MAX; tix[s] = 0x7FFFFFFF; }
  size_t base = (size_t)q * NCH * KTOP;
  for (int m = 0; m < NCH * KTOP; ++m) ins5(tv, tix, pvals[base + m], pidx[base + m]);
  float xq = x2[q];
#pragma unroll
  for (int s = 0; s < KTOP; ++s) {
    float d2 = tv[s] + xq;
    d2 = d2 > 0.f ? d2 : 0.f;
    out[(size_t)q * KTOP + s] = sqrtf(d2);                         // topk_dists [Q,K]
    out[(size_t)NQ * KTOP + (size_t)q * KTOP + s] = (float)tix[s]; // topk_inds [Q,K]
    out[(size_t)2 * NQ * KTOP + (size_t)s * NQ + q] =
        (float)labels[tix[s]];                                      // pred [K,Q]
  }
}

extern "C" void kernel_launch(void* const* d_in, const int* in_sizes, int n_in,
                              void* d_out, int out_size, void* d_ws, size_t ws_size,
                              hipStream_t stream) {
  const float* x = (const float*)d_in[0];
  const float* T = (const float*)d_in[1];
  const int* labels = (const int*)d_in[2];
  float* out = (float*)d_out;
  char* ws = (char*)d_ws;

  // ws layout (bytes)
  float* t2   = (float*)(ws + 0);              // 400000
  float* x2   = (float*)(ws + 401408);         // 8192
  short* xhi  = (short*)(ws + 409600);         // 2,097,152
  short* xmid = (short*)(ws + 2506752);        // 2,097,152
  short* thi  = (short*)(ws + 4603904);        // 105,644,032
  short* tmid = (short*)(ws + 110247936);      // 105,644,032
  float* pvals = (float*)(ws + 215891968);     // 2,539,520
  int*   pidx  = (int*)(ws + 218431488);       // 2,539,520  (end ~221 MB)

  int waves = TPAD + NQ;                        // 105216
  convert_kernel<<<waves / 4, 256, 0, stream>>>(x, T, xhi, xmid, thi, tmid, t2, x2);

  dim3 grid(QBLKS, NCH);                        // 16 x 62 = 992 blocks
  knn_mfma<<<grid, 256, 0, stream>>>(xhi, xmid, thi, tmid, t2, pvals, pidx);

  knn_merge<<<(NQ + 255) / 256, 256, 0, stream>>>(pvals, pidx, x2, labels, out);
}

// Round 4
// 1107.965 us; speedup vs baseline: 1.9712x; 1.9712x over previous
//
#include <hip/hip_runtime.h>
#include <float.h>
#include <math.h>

#define NQ 2048
#define NT 100000
#define DIM 512
#define KTOP 5
#define QTILE 128
#define TTILE 128
#define NTPC 13             // t-tiles per chunk
#define CHUNK (NTPC*TTILE)  // 1664
#define NCH 64              // 64*1664 = 106496 >= 100000; 8 chunks per XCD
#define TPAD 106496
#define QBLKS 16            // NQ/128

typedef float f32x4 __attribute__((ext_vector_type(4)));
typedef short s16x8 __attribute__((ext_vector_type(8)));
typedef unsigned int u32;

__device__ __forceinline__ bool lt_pair(float v1, int i1, float v2, int i2) {
  return v1 < v2 || (v1 == v2 && i1 < i2);
}

__device__ __forceinline__ void ins5(float* tv, int* tix, float sc, int idx) {
  if (lt_pair(sc, idx, tv[4], tix[4])) {
    tv[4] = sc; tix[4] = idx;
#pragma unroll
    for (int p = 4; p > 0; --p)
      if (lt_pair(tv[p], tix[p], tv[p - 1], tix[p - 1])) {
        float tf = tv[p]; tv[p] = tv[p - 1]; tv[p - 1] = tf;
        int tn = tix[p]; tix[p] = tix[p - 1]; tix[p - 1] = tn;
      }
  }
}

__device__ __forceinline__ void merge5(float* av, int* ai, const float* bv, const int* bi) {
  float nv[5]; int ni[5];
#pragma unroll
  for (int s = 0; s < 5; ++s) {
    if (lt_pair(av[s], ai[s], bv[4 - s], bi[4 - s])) { nv[s] = av[s]; ni[s] = ai[s]; }
    else { nv[s] = bv[4 - s]; ni[s] = bi[4 - s]; }
  }
#pragma unroll
  for (int a = 0; a < 5; ++a)
#pragma unroll
    for (int b = 0; b < 4 - a; ++b)
      if (lt_pair(nv[b + 1], ni[b + 1], nv[b], ni[b])) {
        float tf = nv[b]; nv[b] = nv[b + 1]; nv[b + 1] = tf;
        int tn = ni[b]; ni[b] = ni[b + 1]; ni[b + 1] = tn;
      }
#pragma unroll
  for (int s = 0; s < 5; ++s) { av[s] = nv[s]; ai[s] = ni[s]; }
}

// ---------------- convert: fp32 -> frag-major (hi, mid) bf16 + fused norms ----
// dst short-offset = ((blk128*16 + kbi)*512 + tile*64 + l) * 8  (l = quad*16+m)
// i.e. lane l's 16B MFMA fragment for (blk, kbi, tile) is one contiguous load.
__global__ __launch_bounds__(256) void convert_kernel(
    const float* __restrict__ x, const float* __restrict__ T,
    short* __restrict__ xhi, short* __restrict__ xmid,
    short* __restrict__ thi, short* __restrict__ tmid,
    float* __restrict__ t2, float* __restrict__ x2) {
  int gwave = (blockIdx.x * 256 + threadIdx.x) >> 6;
  int l = threadIdx.x & 63;
  if (gwave >= TPAD + NQ) return;
  bool isT = gwave < TPAD;
  int r = isT ? gwave : gwave - TPAD;
  int nsrc = isT ? NT : NQ;
  int rs = r < nsrc ? r : nsrc - 1;   // clamp padded rows
  const float* src = (isT ? T : x) + (size_t)rs * DIM + l * 8;

  f32x4 a = *(const f32x4*)src;
  f32x4 b = *(const f32x4*)(src + 4);
  float e[8] = {a[0], a[1], a[2], a[3], b[0], b[1], b[2], b[3]};
  s16x8 hv, mv;
  float ss = 0.f;
#pragma unroll
  for (int i = 0; i < 8; ++i) {
    ss = fmaf(e[i], e[i], ss);
    u32 u = __builtin_bit_cast(u32, e[i]);
    u32 rr = u + 0x7FFFu + ((u >> 16) & 1u);       // RNE to bf16
    float resid = e[i] - __builtin_bit_cast(float, rr & 0xFFFF0000u);
    u32 u2 = __builtin_bit_cast(u32, resid);
    u32 r2 = u2 + 0x7FFFu + ((u2 >> 16) & 1u);
    hv[i] = (short)(rr >> 16);
    mv[i] = (short)(r2 >> 16);
  }
#pragma unroll
  for (int off = 32; off > 0; off >>= 1) ss += __shfl_down(ss, off, 64);
  if (l == 0 && r < nsrc) (isT ? t2 : x2)[r] = ss;

  int blk = r >> 7, rt = r & 127, tile = rt >> 4, m = rt & 15;
  int kbi = l >> 2, quad = l & 3;
  size_t off = (((size_t)(blk * 16 + kbi)) * 512 + tile * 64 + quad * 16 + m) * 8;
  *(s16x8*)((isT ? thi : xhi) + off) = hv;
  *(s16x8*)((isT ? tmid : xmid) + off) = mv;
}

__device__ __forceinline__ void load_frags(
    const short* __restrict__ xhi, const short* __restrict__ xmid,
    const short* __restrict__ thi, const short* __restrict__ tmid,
    size_t abase, size_t bbase, int arow, int bcol, int l,
    s16x8* ah, s16x8* am, s16x8* bh, s16x8* bm) {
#pragma unroll
  for (int i = 0; i < 4; ++i) {
    size_t ao = abase + (size_t)((arow + i) * 64 + l) * 8;
    size_t bo = bbase + (size_t)((bcol + i) * 64 + l) * 8;
    ah[i] = *(const s16x8*)(xhi + ao);
    am[i] = *(const s16x8*)(xmid + ao);
    bh[i] = *(const s16x8*)(thi + bo);
    bm[i] = *(const s16x8*)(tmid + bo);
  }
}

__device__ __forceinline__ void do_mfma(const s16x8* ah, const s16x8* am,
                                        const s16x8* bh, const s16x8* bm,
                                        f32x4 acc[4][4]) {
#pragma unroll
  for (int j = 0; j < 4; ++j)
#pragma unroll
    for (int i = 0; i < 4; ++i) {
      acc[i][j] = __builtin_amdgcn_mfma_f32_16x16x32_bf16(ah[i], bh[j], acc[i][j], 0, 0, 0);
      acc[i][j] = __builtin_amdgcn_mfma_f32_16x16x32_bf16(ah[i], bm[j], acc[i][j], 0, 0, 0);
      acc[i][j] = __builtin_amdgcn_mfma_f32_16x16x32_bf16(am[i], bh[j], acc[i][j], 0, 0, 0);
    }
}

// ---------------- main: barrier-free K-loop, direct global->VGPR fragments ----
__global__ __launch_bounds__(256, 2) void knn_mfma(
    const short* __restrict__ xhi, const short* __restrict__ xmid,
    const short* __restrict__ thi, const short* __restrict__ tmid,
    const float* __restrict__ t2g,
    float* __restrict__ pvals, int* __restrict__ pidx) {
  __shared__ float scr_all[4 * 1280];  // per-wave epilogue scratch (20 KB)

  const int tid = threadIdx.x;
  const int w = tid >> 6;
  const int l = tid & 63;
  // XCD swizzle: chunk = (bid&7) + 8*(bid>>7)  -> each XCD owns 8 chunks;
  // the 16 q-blocks of one chunk are dispatched to the same XCD (L2-shared B).
  const int bid = blockIdx.x;
  const int sl = bid >> 3;
  const int qblk = sl & 15;
  const int chunk = (bid & 7) + 8 * (sl >> 4);
  const int q0 = qblk * QTILE;
  const int wr = (w >> 1) * 64;
  const int wc = (w & 1) * 64;
  const int arow = wr >> 4;
  const int bcol = wc >> 4;

  float tv[KTOP]; int tix[KTOP];
#pragma unroll
  for (int s = 0; s < KTOP; ++s) { tv[s] = FLT_MAX; tix[s] = 0x7FFFFFFF; }

  for (int tt = 0; tt < NTPC; ++tt) {
    const int bblk = chunk * NTPC + tt;
    const int jbase = bblk * TTILE;
    f32x4 acc[4][4];
#pragma unroll
    for (int i = 0; i < 4; ++i)
#pragma unroll
      for (int j = 0; j < 4; ++j) acc[i][j] = (f32x4){0.f, 0.f, 0.f, 0.f};

    s16x8 ah0[4], am0[4], bh0[4], bm0[4];
    s16x8 ah1[4], am1[4], bh1[4], bm1[4];
#define ABASE(kbi) ((size_t)((qblk * 16 + (kbi)) * 512) * 8)
#define BBASE(kbi) ((size_t)((bblk * 16 + (kbi)) * 512) * 8)
    load_frags(xhi, xmid, thi, tmid, ABASE(0), BBASE(0), arow, bcol, l,
               ah0, am0, bh0, bm0);
#pragma unroll 1
    for (int step = 0; step < 8; ++step) {
      int kbi = step * 2;
      load_frags(xhi, xmid, thi, tmid, ABASE(kbi + 1), BBASE(kbi + 1), arow, bcol, l,
                 ah1, am1, bh1, bm1);
      do_mfma(ah0, am0, bh0, bm0, acc);
      if (step < 7)
        load_frags(xhi, xmid, thi, tmid, ABASE(kbi + 2), BBASE(kbi + 2), arow, bcol, l,
                   ah0, am0, bh0, bm0);
      do_mfma(ah1, am1, bh1, bm1, acc);
    }
#undef ABASE
#undef BBASE

    // epilogue: transpose C through wave-private LDS scratch; per-lane top-5
    float* scr = scr_all + w * 1280;  // 64 rows x 20 (pad)
#pragma unroll
    for (int jj = 0; jj < 4; ++jj) {
      int colg = jbase + wc + jj * 16 + (l & 15);
      int cc = colg < NT ? colg : NT - 1;
      float t2v = t2g[cc];
      bool valid = colg < NT;
#pragma unroll
      for (int i = 0; i < 4; ++i)
#pragma unroll
        for (int r = 0; r < 4; ++r) {
          float sc = valid ? fmaf(-2.f, acc[i][jj][r], t2v) : FLT_MAX;
          int rowl = i * 16 + ((l >> 4) << 2) + r;
          scr[rowl * 20 + (l & 15)] = sc;
        }
      int cbg = jbase + wc + jj * 16;
#pragma unroll
      for (int c4 = 0; c4 < 4; ++c4) {
        f32x4 rv = *(const f32x4*)(scr + l * 20 + c4 * 4);
#pragma unroll
        for (int c = 0; c < 4; ++c) ins5(tv, tix, rv[c], cbg + c4 * 4 + c);
      }
    }
  }

  // cross-wave merge: waves (0,1) share rows 0-63, (2,3) rows 64-127
  __syncthreads();
  float* ms = scr_all;
  int* msi = (int*)scr_all + 640;
  if (w & 1) {
    int rid = wr + l;
#pragma unroll
    for (int s = 0; s < KTOP; ++s) { ms[rid * 5 + s] = tv[s]; msi[rid * 5 + s] = tix[s]; }
  }
  __syncthreads();
  if (!(w & 1)) {
    int rid = wr + l;
    float ov[KTOP]; int oi[KTOP];
#pragma unroll
    for (int s = 0; s < KTOP; ++s) { ov[s] = ms[rid * 5 + s]; oi[s] = msi[rid * 5 + s]; }
    merge5(tv, tix, ov, oi);
    int q = q0 + rid;
    size_t base = ((size_t)q * NCH + chunk) * KTOP;
#pragma unroll
    for (int s = 0; s < KTOP; ++s) { pvals[base + s] = tv[s]; pidx[base + s] = tix[s]; }
  }
}

// ---------------- final merge: 320 candidates -> 5, write outputs ----------------
__global__ __launch_bounds__(256) void knn_merge(
    const float* __restrict__ pvals, const int* __restrict__ pidx,
    const float* __restrict__ x2, const int* __restrict__ labels,
    float* __restrict__ out) {
  int q = blockIdx.x * 256 + threadIdx.x;
  if (q >= NQ) return;
  float tv[KTOP]; int tix[KTOP];
#pragma unroll
  for (int s = 0; s < KTOP; ++s) { tv[s] = FLT_MAX; tix[s] = 0x7FFFFFFF; }
  size_t base = (size_t)q * NCH * KTOP;
  for (int m = 0; m < NCH * KTOP; ++m) ins5(tv, tix, pvals[base + m], pidx[base + m]);
  float xq = x2[q];
#pragma unroll
  for (int s = 0; s < KTOP; ++s) {
    float d2 = tv[s] + xq;
    d2 = d2 > 0.f ? d2 : 0.f;
    out[(size_t)q * KTOP + s] = sqrtf(d2);                         // topk_dists [Q,K]
    out[(size_t)NQ * KTOP + (size_t)q * KTOP + s] = (float)tix[s]; // topk_inds [Q,K]
    out[(size_t)2 * NQ * KTOP + (size_t)s * NQ + q] =
        (float)labels[tix[s]];                                      // pred [K,Q]
  }
}

extern "C" void kernel_launch(void* const* d_in, const int* in_sizes, int n_in,
                              void* d_out, int out_size, void* d_ws, size_t ws_size,
                              hipStream_t stream) {
  const float* x = (const float*)d_in[0];
  const float* T = (const float*)d_in[1];
  const int* labels = (const int*)d_in[2];
  float* out = (float*)d_out;
  char* ws = (char*)d_ws;

  // ws layout (bytes), total ~228 MB
  float* t2   = (float*)(ws + 0);               // 400,000
  float* x2   = (float*)(ws + 401408);          // 8,192
  short* xhi  = (short*)(ws + 409600);          // 2,097,152
  short* xmid = (short*)(ws + 2506752);         // 2,097,152
  short* thi  = (short*)(ws + 4603904);         // 109,051,904
  short* tmid = (short*)(ws + 113655808);       // 109,051,904
  float* pvals = (float*)(ws + 222707712);      // 2,621,440
  int*   pidx  = (int*)(ws + 225329152);        // 2,621,440

  int waves = TPAD + NQ;                         // 108,544
  convert_kernel<<<waves / 4, 256, 0, stream>>>(x, T, xhi, xmid, thi, tmid, t2, x2);

  knn_mfma<<<QBLKS * NCH, 256, 0, stream>>>(xhi, xmid, thi, tmid, t2, pvals, pidx);

  knn_merge<<<(NQ + 255) / 256, 256, 0, stream>>>(pvals, pidx, x2, labels, out);
}

// Round 6
// 1021.432 us; speedup vs baseline: 2.1382x; 1.0847x over previous
//
#include <hip/hip_runtime.h>
#include <float.h>
#include <math.h>

#define NQ 2048
#define NT 100000
#define DIM 512
#define KTOP 5
#define QTILE 128
#define TTILE 128
#define NTPC 13             // t-tiles per chunk
#define CHUNK (NTPC*TTILE)  // 1664
#define NCH 64              // chunk id space; 8 chunks per XCD
#define TBLKS 782           // ceil(NT/128) -> valid 128-row t-tile blocks
#define TPAD (TBLKS*128)    // 100096
#define QBLKS 16            // NQ/128
#define NSUB 4              // t-sub-blocks per chunk (tiles {4,3,3,3})
#define CV_TBLKS (TBLKS*16) // 12512 convert tasks for T
#define CV_XBLKS ((NQ/128)*16) // 256 convert tasks for x

typedef float f32x4 __attribute__((ext_vector_type(4)));
typedef short s16x8 __attribute__((ext_vector_type(8)));
typedef unsigned int u32;

__device__ __forceinline__ bool lt_pair(float v1, int i1, float v2, int i2) {
  return v1 < v2 || (v1 == v2 && i1 < i2);
}

__device__ __forceinline__ void ins5(float* tv, int* tix, float sc, int idx) {
  if (lt_pair(sc, idx, tv[4], tix[4])) {
    tv[4] = sc; tix[4] = idx;
#pragma unroll
    for (int p = 4; p > 0; --p)
      if (lt_pair(tv[p], tix[p], tv[p - 1], tix[p - 1])) {
        float tf = tv[p]; tv[p] = tv[p - 1]; tv[p - 1] = tf;
        int tn = tix[p]; tix[p] = tix[p - 1]; tix[p - 1] = tn;
      }
  }
}

__device__ __forceinline__ void merge5(float* av, int* ai, const float* bv, const int* bi) {
  float nv[5]; int ni[5];
#pragma unroll
  for (int s = 0; s < 5; ++s) {
    if (lt_pair(av[s], ai[s], bv[4 - s], bi[4 - s])) { nv[s] = av[s]; ni[s] = ai[s]; }
    else { nv[s] = bv[4 - s]; ni[s] = bi[4 - s]; }
  }
#pragma unroll
  for (int a = 0; a < 5; ++a)
#pragma unroll
    for (int b = 0; b < 4 - a; ++b)
      if (lt_pair(nv[b + 1], ni[b + 1], nv[b], ni[b])) {
        float tf = nv[b]; nv[b] = nv[b + 1]; nv[b + 1] = tf;
        int tn = ni[b]; ni[b] = ni[b + 1]; ni[b + 1] = tn;
      }
#pragma unroll
  for (int s = 0; s < 5; ++s) { av[s] = nv[s]; ai[s] = ni[s]; }
}

// ---------------- convert: fp32 -> frag-major (hi,mid) bf16, LDS-transposed ----
// One block per (src, blk128, kbi): reads 128 rows x 32 cols fp32 (coalesced
// 128B row segments), converts, transposes to frag order in LDS, writes one
// contiguous 8KB slice per array (fully coalesced: 4096 shorts = 256 thr x 16).
// Norms via atomicAdd of per-(row,kbi) partials (t2/x2 zeroed by memsetAsync).
__global__ __launch_bounds__(256) void convert_kernel(
    const float* __restrict__ x, const float* __restrict__ T,
    short* __restrict__ xhi, short* __restrict__ xmid,
    short* __restrict__ thi, short* __restrict__ tmid,
    float* __restrict__ t2, float* __restrict__ x2) {
  __shared__ short lh[4096];
  __shared__ short lm[4096];
  const int bid = blockIdx.x;
  const bool isT = bid < CV_TBLKS;
  const int task = isT ? bid : bid - CV_TBLKS;
  const int blk = task >> 4, kbi = task & 15;
  const float* src = isT ? T : x;
  short* dhi = isT ? thi : xhi;
  short* dmid = isT ? tmid : xmid;
  float* nrm = isT ? t2 : x2;
  const int nsrc = isT ? NT : NQ;

  const int t = threadIdx.x;
  const int rr = t >> 1, half = t & 1;
  const int grow = blk * 128 + rr;
  const int rs = grow < nsrc ? grow : nsrc - 1;
  const float* p = src + (size_t)rs * DIM + kbi * 32 + half * 16;
  f32x4 v[4];
#pragma unroll
  for (int i = 0; i < 4; ++i) v[i] = ((const f32x4*)p)[i];

  float ss = 0.f;
#pragma unroll
  for (int g = 0; g < 2; ++g) {
    s16x8 hv, mv;
#pragma unroll
    for (int e = 0; e < 8; ++e) {
      int i = g * 8 + e;
      float f = v[i >> 2][i & 3];
      ss = fmaf(f, f, ss);
      u32 u = __builtin_bit_cast(u32, f);
      u32 r1 = u + 0x7FFFu + ((u >> 16) & 1u);        // RNE to bf16
      float resid = f - __builtin_bit_cast(float, r1 & 0xFFFF0000u);
      u32 u2 = __builtin_bit_cast(u32, resid);
      u32 r2 = u2 + 0x7FFFu + ((u2 >> 16) & 1u);
      hv[e] = (short)(r1 >> 16);
      mv[e] = (short)(r2 >> 16);
    }
    // frag unit: tile = rr>>4, quad = half*2+g, m = rr&15
    int unit = (rr >> 4) * 64 + (half * 2 + g) * 16 + (rr & 15);
    *(s16x8*)(lh + unit * 8) = hv;
    *(s16x8*)(lm + unit * 8) = mv;
  }
  ss += __shfl_xor(ss, 1, 64);       // pair (t, t^1) share a row
  if (half == 0 && grow < nsrc) atomicAdd(nrm + grow, ss);

  __syncthreads();
  // slice = 4096 shorts per array; thread t copies shorts [t*16, t*16+16)
  size_t obase = ((size_t)(blk * 16 + kbi)) * 4096 + t * 16;
  *(s16x8*)(dhi + obase)      = *(const s16x8*)(lh + t * 16);
  *(s16x8*)(dhi + obase + 8)  = *(const s16x8*)(lh + t * 16 + 8);
  *(s16x8*)(dmid + obase)     = *(const s16x8*)(lm + t * 16);
  *(s16x8*)(dmid + obase + 8) = *(const s16x8*)(lm + t * 16 + 8);
}

__device__ __forceinline__ void load_frags(
    const short* __restrict__ xhi, const short* __restrict__ xmid,
    const short* __restrict__ thi, const short* __restrict__ tmid,
    size_t abase, size_t bbase, int arow, int bcol, int l,
    s16x8* ah, s16x8* am, s16x8* bh, s16x8* bm) {
#pragma unroll
  for (int i = 0; i < 4; ++i) {
    size_t ao = abase + (size_t)((arow + i) * 64 + l) * 8;
    size_t bo = bbase + (size_t)((bcol + i) * 64 + l) * 8;
    ah[i] = *(const s16x8*)(xhi + ao);
    am[i] = *(const s16x8*)(xmid + ao);
    bh[i] = *(const s16x8*)(thi + bo);
    bm[i] = *(const s16x8*)(tmid + bo);
  }
}

__device__ __forceinline__ void do_mfma(const s16x8* ah, const s16x8* am,
                                        const s16x8* bh, const s16x8* bm,
                                        f32x4 acc[4][4]) {
#pragma unroll
  for (int j = 0; j < 4; ++j)
#pragma unroll
    for (int i = 0; i < 4; ++i) {
      acc[i][j] = __builtin_amdgcn_mfma_f32_16x16x32_bf16(ah[i], bh[j], acc[i][j], 0, 0, 0);
      acc[i][j] = __builtin_amdgcn_mfma_f32_16x16x32_bf16(ah[i], bm[j], acc[i][j], 0, 0, 0);
      acc[i][j] = __builtin_amdgcn_mfma_f32_16x16x32_bf16(am[i], bh[j], acc[i][j], 0, 0, 0);
    }
}

// ---------------- main: barrier-free K-loop, direct global->VGPR fragments ----
// Grid 4096: bid = xcd + 8*(inner + 64*chunkHigh); inner = tsub*16 + qblk.
// Per XCD the 64 co-resident blocks (2/CU x 32 CU) = 16 qblk x 4 tsub of ONE
// chunk -> B working set 13 tiles x 256KB = 3.3 MB, fits the 4 MB XCD L2.
__global__ __launch_bounds__(256, 2) void knn_mfma(
    const short* __restrict__ xhi, const short* __restrict__ xmid,
    const short* __restrict__ thi, const short* __restrict__ tmid,
    const float* __restrict__ t2g,
    float* __restrict__ pvals, int* __restrict__ pidx) {
  __shared__ float scr_all[4 * 1280];  // per-wave epilogue scratch (20 KB)

  const int tid = threadIdx.x;
  const int w = tid >> 6;
  const int l = tid & 63;
  const int bid = blockIdx.x;
  const int rest = bid >> 3;
  const int inner = rest & 63;
  const int chunk = (bid & 7) + 8 * (rest >> 6);
  const int qblk = inner & 15;
  const int tsub = inner >> 4;                 // 0..3
  const int tstart = (13 * tsub + 3) >> 2;     // {0,4,7,10}
  const int tend = (13 * (tsub + 1) + 3) >> 2; // {4,7,10,13}
  const int q0 = qblk * QTILE;
  const int wr = (w >> 1) * 64;
  const int wc = (w & 1) * 64;
  const int arow = wr >> 4;
  const int bcol = wc >> 4;

  float tv[KTOP]; int tix[KTOP];
#pragma unroll
  for (int s = 0; s < KTOP; ++s) { tv[s] = FLT_MAX; tix[s] = 0x7FFFFFFF; }

#pragma unroll 1
  for (int tt = tstart; tt < tend; ++tt) {
    const int bblk = chunk * NTPC + tt;
    if (bblk >= TBLKS) continue;   // fully past NT: partials stay FLT_MAX
    const int jbase = bblk * TTILE;
    f32x4 acc[4][4];
#pragma unroll
    for (int i = 0; i < 4; ++i)
#pragma unroll
      for (int j = 0; j < 4; ++j) acc[i][j] = (f32x4){0.f, 0.f, 0.f, 0.f};

    s16x8 ah0[4], am0[4], bh0[4], bm0[4];
    s16x8 ah1[4], am1[4], bh1[4], bm1[4];
#define ABASE(kbi) ((size_t)((qblk * 16 + (kbi)) * 512) * 8)
#define BBASE(kbi) ((size_t)((bblk * 16 + (kbi)) * 512) * 8)
    load_frags(xhi, xmid, thi, tmid, ABASE(0), BBASE(0), arow, bcol, l,
               ah0, am0, bh0, bm0);
#pragma unroll 1
    for (int step = 0; step < 8; ++step) {
      int kbi = step * 2;
      load_frags(xhi, xmid, thi, tmid, ABASE(kbi + 1), BBASE(kbi + 1), arow, bcol, l,
                 ah1, am1, bh1, bm1);
      do_mfma(ah0, am0, bh0, bm0, acc);
      if (step < 7)
        load_frags(xhi, xmid, thi, tmid, ABASE(kbi + 2), BBASE(kbi + 2), arow, bcol, l,
                   ah0, am0, bh0, bm0);
      do_mfma(ah1, am1, bh1, bm1, acc);
    }
#undef ABASE
#undef BBASE

    // epilogue: transpose C through wave-private LDS scratch; per-lane top-5
    float* scr = scr_all + w * 1280;  // 64 rows x 20 (pad)
#pragma unroll
    for (int jj = 0; jj < 4; ++jj) {
      int colg = jbase + wc + jj * 16 + (l & 15);
      int cc = colg < NT ? colg : NT - 1;
      float t2v = t2g[cc];
      bool valid = colg < NT;
#pragma unroll
      for (int i = 0; i < 4; ++i)
#pragma unroll
        for (int r = 0; r < 4; ++r) {
          float sc = valid ? fmaf(-2.f, acc[i][jj][r], t2v) : FLT_MAX;
          int rowl = i * 16 + ((l >> 4) << 2) + r;
          scr[rowl * 20 + (l & 15)] = sc;
        }
      int cbg = jbase + wc + jj * 16;
#pragma unroll
      for (int c4 = 0; c4 < 4; ++c4) {
        f32x4 rv = *(const f32x4*)(scr + l * 20 + c4 * 4);
#pragma unroll
        for (int c = 0; c < 4; ++c) ins5(tv, tix, rv[c], cbg + c4 * 4 + c);
      }
    }
  }

  // cross-wave merge: waves (0,1) share rows 0-63, (2,3) rows 64-127
  __syncthreads();
  float* ms = scr_all;
  int* msi = (int*)scr_all + 640;
  if (w & 1) {
    int rid = wr + l;
#pragma unroll
    for (int s = 0; s < KTOP; ++s) { ms[rid * 5 + s] = tv[s]; msi[rid * 5 + s] = tix[s]; }
  }
  __syncthreads();
  if (!(w & 1)) {
    int rid = wr + l;
    float ov[KTOP]; int oi[KTOP];
#pragma unroll
    for (int s = 0; s < KTOP; ++s) { ov[s] = ms[rid * 5 + s]; oi[s] = msi[rid * 5 + s]; }
    merge5(tv, tix, ov, oi);
    int q = q0 + rid;
    size_t base = ((size_t)q * (NCH * NSUB) + (chunk * NSUB + tsub)) * KTOP;
#pragma unroll
    for (int s = 0; s < KTOP; ++s) { pvals[base + s] = tv[s]; pidx[base + s] = tix[s]; }
  }
}

// ---------------- final merge: one wave per query, 1280 candidates -> 5 ------
__global__ __launch_bounds__(256) void knn_merge(
    const float* __restrict__ pvals, const int* __restrict__ pidx,
    const float* __restrict__ x2, const int* __restrict__ labels,
    float* __restrict__ out) {
  const int M = NCH * NSUB * KTOP;  // 1280
  int q = (blockIdx.x * 256 + threadIdx.x) >> 6;
  int l = threadIdx.x & 63;
  if (q >= NQ) return;
  float tv[KTOP]; int tix[KTOP];
#pragma unroll
  for (int s = 0; s < KTOP; ++s) { tv[s] = FLT_MAX; tix[s] = 0x7FFFFFFF; }
  size_t base = (size_t)q * M;
#pragma unroll 1
  for (int m = l; m < M; m += 64) ins5(tv, tix, pvals[base + m], pidx[base + m]);
#pragma unroll
  for (int d = 32; d >= 1; d >>= 1) {
    float ov[KTOP]; int oi[KTOP];
#pragma unroll
    for (int s = 0; s < KTOP; ++s) {
      ov[s] = __shfl_down(tv[s], d, 64);
      oi[s] = __shfl_down(tix[s], d, 64);
    }
    merge5(tv, tix, ov, oi);
  }
  if (l == 0) {
    float xq = x2[q];
#pragma unroll
    for (int s = 0; s < KTOP; ++s) {
      float d2 = tv[s] + xq;
      d2 = d2 > 0.f ? d2 : 0.f;
      out[(size_t)q * KTOP + s] = sqrtf(d2);                         // topk_dists [Q,K]
      out[(size_t)NQ * KTOP + (size_t)q * KTOP + s] = (float)tix[s]; // topk_inds [Q,K]
      out[(size_t)2 * NQ * KTOP + (size_t)s * NQ + q] =
          (float)labels[tix[s]];                                      // pred [K,Q]
    }
  }
}

extern "C" void kernel_launch(void* const* d_in, const int* in_sizes, int n_in,
                              void* d_out, int out_size, void* d_ws, size_t ws_size,
                              hipStream_t stream) {
  const float* x = (const float*)d_in[0];
  const float* T = (const float*)d_in[1];
  const int* labels = (const int*)d_in[2];
  float* out = (float*)d_out;
  char* ws = (char*)d_ws;

  // ws layout (bytes), total ~230.6 MB (R4's proven footprint was ~235.8 MB)
  float* t2   = (float*)(ws + 0);               // 400,000
  float* x2   = (float*)(ws + 401408);          // 8,192
  short* xhi  = (short*)(ws + 409600);          // 2,097,152
  short* xmid = (short*)(ws + 2506752);         // 2,097,152
  short* thi  = (short*)(ws + 4603904);         // 102,498,304
  short* tmid = (short*)(ws + 107102208);       // 102,498,304
  float* pvals = (float*)(ws + 209600512);      // 10,485,760
  int*   pidx  = (int*)(ws + 220086272);        // 10,485,760 (end 230,572,032)

  hipMemsetAsync(ws, 0, 409600, stream);        // zero t2/x2 for atomic norms

  convert_kernel<<<CV_TBLKS + CV_XBLKS, 256, 0, stream>>>(
      x, T, xhi, xmid, thi, tmid, t2, x2);

  knn_mfma<<<QBLKS * NSUB * NCH, 256, 0, stream>>>(
      xhi, xmid, thi, tmid, t2, pvals, pidx);

  knn_merge<<<(NQ * 64 + 255) / 256, 256, 0, stream>>>(pvals, pidx, x2, labels, out);
}